// Round 7
// baseline (794.001 us; speedup 1.0000x reference)
//
#include <hip/hip_runtime.h>
#include <hip/hip_bf16.h>
#include <stdint.h>

// ---------------- problem constants ----------------
constexpr int NN = 100000;     // nodes
constexpr int NE = 1600000;    // edges
constexpr int NG = 64;         // graphs
constexpr int S  = 192;        // row stride (elements) for node-feature buffers
constexpr int NB_SCAN = 98;    // ceil(100000/1024)
constexpr int CSR_PASSES = 2;  // dst-range passes for L2-resident scatter (3.4MB slice < 4MiB L2)
constexpr int PASS_W = 50000;  // NN / CSR_PASSES
constexpr unsigned int ZOFF = (unsigned int)NN * 384u;   // byte offset of the zero row

typedef __bf16 bf16x8 __attribute__((ext_vector_type(8)));
typedef float  f32x16 __attribute__((ext_vector_type(16)));
typedef float  f32x2  __attribute__((ext_vector_type(2)));

union U16x4 { uint4 u; bf16x8 b; };

// bf16(packed in uint halves) <-> f32 helpers
__device__ __forceinline__ float bl(unsigned int u) { return __uint_as_float(u << 16); }
__device__ __forceinline__ float bh(unsigned int u) { return __uint_as_float(u & 0xffff0000u); }
__device__ __forceinline__ unsigned int fb(float f) {  // f32 -> bf16 bits, RTNE
    unsigned int u = __float_as_uint(f);
    return (u + 0x7fffu + ((u >> 16) & 1u)) >> 16;
}
// packed bf16 relu: v_pk_max_f16 on raw bits decides on sign/zero only — exact for bf16.
__device__ __forceinline__ unsigned int prelu(unsigned int u) {
    unsigned int r;
    asm("v_pk_max_f16 %0, %1, %2" : "=v"(r) : "v"(u), "v"(0u));
    return r;
}

// ---------------- preprocessing kernels ----------------
__global__ __launch_bounds__(256) void k_indeg(const int* __restrict__ ei, int* __restrict__ indeg) {
    int e4 = (blockIdx.x * 256 + threadIdx.x) * 4;
    if (e4 < NE) {
        int4 d = *(const int4*)(ei + NE + e4);
        atomicAdd(&indeg[d.x], 1);
        atomicAdd(&indeg[d.y], 1);
        atomicAdd(&indeg[d.z], 1);
        atomicAdd(&indeg[d.w], 1);
    }
}

__global__ __launch_bounds__(1024) void k_scan1(const int* __restrict__ indeg, int* __restrict__ offs,
                                                int* __restrict__ partials) {
    __shared__ int s[1024];
    int t = threadIdx.x;
    int gid = blockIdx.x * 1024 + t;
    int v = (gid < NN) ? indeg[gid] : 0;
    s[t] = v;
    __syncthreads();
    for (int d = 1; d < 1024; d <<= 1) {
        int tv = (t >= d) ? s[t - d] : 0;
        __syncthreads();
        s[t] += tv;
        __syncthreads();
    }
    if (gid < NN) offs[gid + 1] = s[t];
    if (t == 1023) partials[blockIdx.x] = s[1023];
}

// parallel exclusive scan of the NB_SCAN block partials (one block)
__global__ __launch_bounds__(128) void k_scan2(int* __restrict__ offs, int* __restrict__ partials) {
    __shared__ int s[128];
    int t = threadIdx.x;
    int v = (t < NB_SCAN) ? partials[t] : 0;
    s[t] = v;
    __syncthreads();
    for (int d = 1; d < 128; d <<= 1) {
        int tv = (t >= d) ? s[t - d] : 0;
        __syncthreads();
        s[t] += tv;
        __syncthreads();
    }
    if (t < NB_SCAN) partials[t] = s[t] - v;   // exclusive
    if (t == 0) offs[0] = 0;
}

__global__ __launch_bounds__(1024) void k_scan3(int* __restrict__ offs, const int* __restrict__ partials) {
    int gid = blockIdx.x * 1024 + threadIdx.x;
    if (gid < NN) offs[gid + 1] += partials[blockIdx.x];
}

// one dst-range pass of the CSR scatter (write region stays L2-resident)
__global__ __launch_bounds__(256) void k_csr(const int* __restrict__ ei, const int* __restrict__ offs,
                                             int* __restrict__ cursor, int* __restrict__ csr,
                                             int lo, int hi) {
    int e2 = (blockIdx.x * 256 + threadIdx.x) * 2;
    if (e2 >= NE) return;
    int2 sv = *(const int2*)(ei + e2);
    int2 dv = *(const int2*)(ei + NE + e2);
    if (dv.x >= lo && dv.x < hi) {
        int pos = offs[dv.x] + atomicAdd(&cursor[dv.x], 1);
        csr[pos] = sv.x;
    }
    if (dv.y >= lo && dv.y < hi) {
        int pos = offs[dv.y] + atomicAdd(&cursor[dv.y], 1);
        csr[pos] = sv.y;
    }
}

// x f32 [NN,128] -> A0 bf16 (stride 192); also zeroes the sentinel row NN
__global__ __launch_bounds__(256) void k_convx(const float* __restrict__ x, unsigned short* __restrict__ A_) {
    int id = blockIdx.x * 256 + threadIdx.x;   // one float4 each; total NN*128/4
    if (id < 96) ((unsigned int*)(A_ + (size_t)NN * S))[id] = 0u;   // zero row
    if (id >= NN * 32) return;
    int row = id >> 5;
    int c4  = id & 31;
    float4 v = ((const float4*)x)[id];
    uint2 a;
    a.x = fb(v.x) | (fb(v.y) << 16);
    a.y = fb(v.z) | (fb(v.w) << 16);
    *(uint2*)(A_ + row * S + c4 * 4) = a;
}

// all four W -> chunk-major bf16 in one dispatch: Wt[(k/8)*N + n][j] = W[(k/8)*8+j, n]
__global__ __launch_bounds__(256) void k_convw4(const float* __restrict__ W0, const float* __restrict__ W1,
                                                const float* __restrict__ W2, const float* __restrict__ W3,
                                                unsigned short* __restrict__ T0, unsigned short* __restrict__ T1,
                                                unsigned short* __restrict__ T2, unsigned short* __restrict__ T3) {
    int id = blockIdx.x * 256 + threadIdx.x;
    const float* W; unsigned short* T; int N, base;
    if      (id <  24576) { W = W0; T = T0; N = 192; base = 0;     }
    else if (id <  61440) { W = W1; T = T1; N = 192; base = 24576; }
    else if (id <  98304) { W = W2; T = T2; N = 192; base = 61440; }
    else if (id < 122880) { W = W3; T = T3; N = 128; base = 98304; }
    else return;
    int lid = id - base;
    int ci = lid >> 3, j = lid & 7;
    int kc = ci / N, n = ci % N;
    T[lid] = (unsigned short)fb(W[(kc * 8 + j) * N + n]);
}

// ---------------- aggregation: y[i] = x[i] + eps*deg + sum relu(A[src]) -> Yout ----------------
// One wave per node; per-edge index work is scalar (s_load edge ids, s_cselect tail->zero row).
// D=192: 48 lanes x 4 feats (dwordx2); D=128: 64 lanes x 2 feats (dword).
__global__ __launch_bounds__(256, 8) void k_agg192(const unsigned short* __restrict__ Ain,
                                                   unsigned short* __restrict__ Yout,
                                                   const int* __restrict__ offs,
                                                   const int* __restrict__ indeg,
                                                   const int* __restrict__ csr) {
    const int w = threadIdx.x >> 6, lane = threadIdx.x & 63;
    const int i = __builtin_amdgcn_readfirstlane(blockIdx.x * 4 + w);
    const bool act = lane < 48;
    const int deg   = __builtin_amdgcn_readfirstlane(indeg[i]);
    const int start = __builtin_amdgcn_readfirstlane(offs[i]);
    const int fo = (act ? lane : 47) * 8;          // clamped byte offset within row
    const char* Ab = (const char*)Ain;

    f32x2 A01, A23;
    {   // residual (not relu'd) + eps*deg
        uint2 p = *(const uint2*)(Ab + (size_t)i * 384 + fo);
        const float ed = 1e-7f * (float)deg;
        A01 = (f32x2){bl(p.x) + ed, bh(p.x) + ed};
        A23 = (f32x2){bl(p.y) + ed, bh(p.y) + ed};
    }

    const int* ecsr = csr + start;                 // wave-uniform
    for (int e = 0; e < deg; e += 16) {
        unsigned int off[16];
#pragma unroll
        for (int k = 0; k < 16; k++) {
            int v = ecsr[e + k];                   // uniform -> s_load (over-read is ws slack)
            off[k] = (e + k < deg) ? (unsigned int)v * 384u : ZOFF;   // s_cselect
        }
        uint2 p[16];
#pragma unroll
        for (int k = 0; k < 16; k++)
            p[k] = *(const uint2*)(Ab + (size_t)off[k] + fo);   // sgpr-base + lane offset
#pragma unroll
        for (int k = 0; k < 16; k++) {
            unsigned int rx = prelu(p[k].x), ry = prelu(p[k].y);
            A01 += (f32x2){bl(rx), bh(rx)};
            A23 += (f32x2){bl(ry), bh(ry)};
        }
    }
    if (act) {
        uint2 o;
        o.x = fb(A01.x) | (fb(A01.y) << 16);
        o.y = fb(A23.x) | (fb(A23.y) << 16);
        *(uint2*)(Yout + (size_t)i * S + lane * 4) = o;
    }
}

__global__ __launch_bounds__(256, 8) void k_agg128(const unsigned short* __restrict__ Ain,
                                                   unsigned short* __restrict__ Yout,
                                                   const int* __restrict__ offs,
                                                   const int* __restrict__ indeg,
                                                   const int* __restrict__ csr) {
    const int w = threadIdx.x >> 6, lane = threadIdx.x & 63;
    const int i = __builtin_amdgcn_readfirstlane(blockIdx.x * 4 + w);
    const int deg   = __builtin_amdgcn_readfirstlane(indeg[i]);
    const int start = __builtin_amdgcn_readfirstlane(offs[i]);
    const int fo = lane * 4;                       // 64 lanes x 2 feats = 256B row payload
    const char* Ab = (const char*)Ain;

    f32x2 A01;
    {
        unsigned int p = *(const unsigned int*)(Ab + (size_t)i * 384 + fo);
        const float ed = 1e-7f * (float)deg;
        A01 = (f32x2){bl(p) + ed, bh(p) + ed};
    }

    const int* ecsr = csr + start;
    for (int e = 0; e < deg; e += 16) {
        unsigned int off[16];
#pragma unroll
        for (int k = 0; k < 16; k++) {
            int v = ecsr[e + k];
            off[k] = (e + k < deg) ? (unsigned int)v * 384u : ZOFF;
        }
        unsigned int q[16];
#pragma unroll
        for (int k = 0; k < 16; k++)
            q[k] = *(const unsigned int*)(Ab + (size_t)off[k] + fo);
#pragma unroll
        for (int k = 0; k < 16; k++) {
            unsigned int r = prelu(q[k]);
            A01 += (f32x2){bl(r), bh(r)};
        }
    }
    *(unsigned int*)(Yout + (size_t)i * S + lane * 2) =
        fb(A01.x) | (fb(A01.y) << 16);
}

// ---------------- GEMM: h = y @ W + b ----------------
// Operands SWAPPED: mfma(A=W-frag, B=y-frag) -> D[wcol][yrow]; lane = output row,
// regs (r&3)+8(r>>2)+4hl = output col -> 4 consecutive bf16 cols pack into dwordx2 stores.
template <int K, int N>
__global__ __launch_bounds__(256) void k_gemm(const unsigned short* __restrict__ Yin,
                                              const unsigned short* __restrict__ WtC,
                                              const float* __restrict__ bias,
                                              unsigned short* __restrict__ Aout) {
    static_assert(K % 16 == 0 && N % 32 == 0, "");
    const int w = threadIdx.x >> 6, lane = threadIdx.x & 63;
    const int rt = blockIdx.x * 4 + w;
    if (rt >= (NN / 32)) return;
    const int hl = lane >> 5, lr = lane & 31;
    const int row0 = rt * 32;
    f32x16 acc[N / 32];
#pragma unroll
    for (int c = 0; c < N / 32; c++)
#pragma unroll
        for (int r = 0; r < 16; r++) acc[c][r] = 0.f;

    const unsigned short* ap = Yin + (row0 + lr) * S + hl * 8;
    const uint4* b4 = (const uint4*)WtC;
#pragma unroll
    for (int ks = 0; ks < K / 16; ks++) {
        U16x4 a;
        a.u = *(const uint4*)(ap + ks * 16);       // y[row=lr][k-half hl] -> B-operand
#pragma unroll
        for (int c = 0; c < N / 32; c++) {
            U16x4 b;
            b.u = b4[(ks * 2 + hl) * N + c * 32 + lr];   // W[k][col=lr] -> A-operand
            acc[c] = __builtin_amdgcn_mfma_f32_32x32x16_bf16(b.b, a.b, acc[c], 0, 0, 0);
        }
    }
    const int row = row0 + lr;
#pragma unroll
    for (int c = 0; c < N / 32; c++) {
#pragma unroll
        for (int g = 0; g < 4; g++) {
            const int col0 = c * 32 + 8 * g + 4 * hl;
            float4 bc = *(const float4*)(bias + col0);
            float v0 = acc[c][4 * g + 0] + bc.x;
            float v1 = acc[c][4 * g + 1] + bc.y;
            float v2 = acc[c][4 * g + 2] + bc.z;
            float v3 = acc[c][4 * g + 3] + bc.w;
            uint2 o;
            o.x = fb(v0) | (fb(v1) << 16);
            o.y = fb(v2) | (fb(v3) << 16);
            *(uint2*)(Aout + (size_t)row * S + col0) = o;
        }
    }
}

// ---------------- pooling + head ----------------
__global__ __launch_bounds__(128) void k_pool(const unsigned short* __restrict__ A_, const int* __restrict__ batch,
                                              float* __restrict__ sums, float* __restrict__ cnt) {
    const int b = blockIdx.x;      // 1000 blocks x 100 nodes
    const int f = threadIdx.x;     // 128 features
    int n0 = b * 100;
    int n1 = min(n0 + 100, NN);
    int cur = batch[n0];
    float acc = 0.f;
    int run = 0;
    for (int n = n0; n < n1; n++) {
        int g = batch[n];
        if (g != cur) {
            atomicAdd(&sums[cur * 128 + f], acc);
            if (f == 0) atomicAdd(&cnt[cur], (float)run);
            acc = 0.f; run = 0; cur = g;
        }
        acc += __uint_as_float(((unsigned int)A_[(size_t)n * S + f]) << 16);
        run++;
    }
    atomicAdd(&sums[cur * 128 + f], acc);
    if (f == 0) atomicAdd(&cnt[cur], (float)run);
}

__global__ __launch_bounds__(64) void k_head(const float* __restrict__ sums, const float* __restrict__ cnt,
                                             const float* __restrict__ Wfc, const float* __restrict__ bfc,
                                             float* __restrict__ out) {
    __shared__ float pooled[128];
    __shared__ float lg[10];
    const int g = blockIdx.x, t = threadIdx.x;
    float inv = 1.f / fmaxf(cnt[g], 1.f);
    pooled[t]      = sums[g * 128 + t] * inv;
    pooled[t + 64] = sums[g * 128 + t + 64] * inv;
    __syncthreads();
    if (t < 10) {
        float s = bfc[t];
        for (int f = 0; f < 128; f++) s += pooled[f] * Wfc[f * 10 + t];
        lg[t] = s;
    }
    __syncthreads();
    if (t < 10) {
        float m = lg[0];
        for (int k = 1; k < 10; k++) m = fmaxf(m, lg[k]);
        float se = 0.f;
        for (int k = 0; k < 10; k++) se += expf(lg[k] - m);
        out[g * 10 + t] = lg[t] - m - logf(se);
    }
}

// ---------------- workspace layout (bytes) ----------------
constexpr size_t A0_OFF     = 0;                    // 38,400,384 (incl zero row NN)
constexpr size_t A1_OFF     = 38400384;             // 38,400,000
constexpr size_t CSR_OFF    = 76800384;             // 6,400,000
constexpr size_t OFFS_OFF   = 83200384;             // 400,128 (100001 ints padded)
constexpr size_t INDEG_OFF  = 83600512;             // 400,000
constexpr size_t CURSOR_OFF = 84000512;             // 400,000
constexpr size_t PART_OFF   = 84400512;             // 512
constexpr size_t WT0_OFF    = 84401024;             // 49,152
constexpr size_t WT1_OFF    = 84450176;             // 73,728
constexpr size_t WT2_OFF    = 84523904;             // 73,728
constexpr size_t WT3_OFF    = 84597632;             // 49,152
constexpr size_t SUMS_OFF   = 84646784;             // 32,768
constexpr size_t CNT_OFF    = 84679552;             // 256

extern "C" void kernel_launch(void* const* d_in, const int* in_sizes, int n_in,
                              void* d_out, int out_size, void* d_ws, size_t ws_size,
                              hipStream_t stream) {
    const float* x   = (const float*)d_in[0];
    const float* W0  = (const float*)d_in[1];
    const float* b0  = (const float*)d_in[2];
    const float* W1  = (const float*)d_in[3];
    const float* b1  = (const float*)d_in[4];
    const float* W2  = (const float*)d_in[5];
    const float* b2  = (const float*)d_in[6];
    const float* W3  = (const float*)d_in[7];
    const float* b3  = (const float*)d_in[8];
    const float* Wfc = (const float*)d_in[9];
    const float* bfc = (const float*)d_in[10];
    const int*   ei  = (const int*)d_in[11];
    const int*   bat = (const int*)d_in[12];
    float* out = (float*)d_out;

    char* ws = (char*)d_ws;
    unsigned short* A0  = (unsigned short*)(ws + A0_OFF);
    unsigned short* A1  = (unsigned short*)(ws + A1_OFF);
    int* csr    = (int*)(ws + CSR_OFF);
    int* offs   = (int*)(ws + OFFS_OFF);
    int* indeg  = (int*)(ws + INDEG_OFF);
    int* cursor = (int*)(ws + CURSOR_OFF);
    int* part   = (int*)(ws + PART_OFF);
    unsigned short* Wt0 = (unsigned short*)(ws + WT0_OFF);
    unsigned short* Wt1 = (unsigned short*)(ws + WT1_OFF);
    unsigned short* Wt2 = (unsigned short*)(ws + WT2_OFF);
    unsigned short* Wt3 = (unsigned short*)(ws + WT3_OFF);
    float* sums = (float*)(ws + SUMS_OFF);
    float* cnt  = (float*)(ws + CNT_OFF);

    // zero indeg+cursor (contiguous) and pool sums+cnt (contiguous)
    hipMemsetAsync(ws + INDEG_OFF, 0, 800000, stream);
    hipMemsetAsync(ws + SUMS_OFF, 0, 33024, stream);

    // CSR build
    k_indeg<<<(NE / 4 + 255) / 256, 256, 0, stream>>>(ei, indeg);
    k_scan1<<<NB_SCAN, 1024, 0, stream>>>(indeg, offs, part);
    k_scan2<<<1, 128, 0, stream>>>(offs, part);
    k_scan3<<<NB_SCAN, 1024, 0, stream>>>(offs, part);
    for (int p = 0; p < CSR_PASSES; p++)
        k_csr<<<NE / 512, 256, 0, stream>>>(ei, offs, cursor, csr, p * PASS_W, (p + 1) * PASS_W);

    // input + weight conversion
    k_convx<<<NN * 32 / 256, 256, 0, stream>>>(x, A0);
    k_convw4<<<480, 256, 0, stream>>>(W0, W1, W2, W3, Wt0, Wt1, Wt2, Wt3);

    const int AGG_GRID  = NN / 4;                   // 25000 blocks, 1 wave/node
    const int GEMM_GRID = (NN / 32 + 3) / 4;        // 782 blocks, 1 wave/32-row tile

    // ping-pong: x/h live in A0 (with zero row), y lives in A1
    k_agg128<<<AGG_GRID, 256, 0, stream>>>(A0, A1, offs, indeg, csr);
    k_gemm<128, 192><<<GEMM_GRID, 256, 0, stream>>>(A1, Wt0, b0, A0);
    k_agg192<<<AGG_GRID, 256, 0, stream>>>(A0, A1, offs, indeg, csr);
    k_gemm<192, 192><<<GEMM_GRID, 256, 0, stream>>>(A1, Wt1, b1, A0);
    k_agg192<<<AGG_GRID, 256, 0, stream>>>(A0, A1, offs, indeg, csr);
    k_gemm<192, 192><<<GEMM_GRID, 256, 0, stream>>>(A1, Wt2, b2, A0);
    k_agg192<<<AGG_GRID, 256, 0, stream>>>(A0, A1, offs, indeg, csr);
    k_gemm<192, 128><<<GEMM_GRID, 256, 0, stream>>>(A1, Wt3, b3, A0);

    // pool + head
    k_pool<<<1000, 128, 0, stream>>>(A0, bat, sums, cnt);
    k_head<<<NG, 64, 0, stream>>>(sums, cnt, Wfc, bfc, out);
}

// Round 8
// 720.569 us; speedup vs baseline: 1.1019x; 1.1019x over previous
//
#include <hip/hip_runtime.h>
#include <hip/hip_bf16.h>
#include <stdint.h>

// ---------------- problem constants ----------------
constexpr int NN = 100000;     // nodes
constexpr int NE = 1600000;    // edges
constexpr int NG = 64;         // graphs
constexpr int S  = 192;        // row stride (elements) for node-feature buffers
constexpr int NB_SCAN = 98;    // ceil(100000/1024)
constexpr unsigned int ZOFF = (unsigned int)NN * 384u;   // byte offset of the zero row

// prep kernel grid sections
constexpr int PREP_CONVX_BLK = 12500;   // NN*32/256
constexpr int PREP_INDEG_BLK = 1563;    // ceil(NE/4/256)
constexpr int PREP_CONVW_BLK = 480;     // 122880/256
constexpr int PREP_GRID = PREP_CONVX_BLK + PREP_INDEG_BLK + PREP_CONVW_BLK;

typedef __bf16 bf16x8 __attribute__((ext_vector_type(8)));
typedef float  f32x16 __attribute__((ext_vector_type(16)));
typedef float  f32x2  __attribute__((ext_vector_type(2)));

union U16x4 { uint4 u; bf16x8 b; };

// bf16(packed in uint halves) <-> f32 helpers
__device__ __forceinline__ float bl(unsigned int u) { return __uint_as_float(u << 16); }
__device__ __forceinline__ float bh(unsigned int u) { return __uint_as_float(u & 0xffff0000u); }
__device__ __forceinline__ unsigned int fb(float f) {  // f32 -> bf16 bits, RTNE
    unsigned int u = __float_as_uint(f);
    return (u + 0x7fffu + ((u >> 16) & 1u)) >> 16;
}
// packed bf16 relu: v_pk_max_f16 on raw bits decides on sign/zero only — exact for bf16.
__device__ __forceinline__ unsigned int prelu(unsigned int u) {
    unsigned int r;
    asm("v_pk_max_f16 %0, %1, %2" : "=v"(r) : "v"(u), "v"(0u));
    return r;
}

// ---------------- fused preprocessing: convx | indeg+slot | convw4 ----------------
__global__ __launch_bounds__(256) void k_prep(const float* __restrict__ x,
                                              const int* __restrict__ ei,
                                              const float* __restrict__ W0, const float* __restrict__ W1,
                                              const float* __restrict__ W2, const float* __restrict__ W3,
                                              unsigned short* __restrict__ A_,
                                              int* __restrict__ indeg, int* __restrict__ slot,
                                              unsigned short* __restrict__ T0, unsigned short* __restrict__ T1,
                                              unsigned short* __restrict__ T2, unsigned short* __restrict__ T3) {
    const int b = blockIdx.x;
    if (b < PREP_CONVX_BLK) {
        // x f32 [NN,128] -> A0 bf16 (stride 192); zero sentinel row NN
        int id = b * 256 + threadIdx.x;
        if (id < 96) ((unsigned int*)(A_ + (size_t)NN * S))[id] = 0u;
        int row = id >> 5, c4 = id & 31;
        float4 v = ((const float4*)x)[id];
        uint2 a;
        a.x = fb(v.x) | (fb(v.y) << 16);
        a.y = fb(v.z) | (fb(v.w) << 16);
        *(uint2*)(A_ + row * S + c4 * 4) = a;
    } else if (b < PREP_CONVX_BLK + PREP_INDEG_BLK) {
        // indeg histogram; atomic return value = edge's slot within its dst segment
        int e4 = ((b - PREP_CONVX_BLK) * 256 + threadIdx.x) * 4;
        if (e4 < NE) {
            int4 d = *(const int4*)(ei + NE + e4);
            int4 sl;
            sl.x = atomicAdd(&indeg[d.x], 1);
            sl.y = atomicAdd(&indeg[d.y], 1);
            sl.z = atomicAdd(&indeg[d.z], 1);
            sl.w = atomicAdd(&indeg[d.w], 1);
            *(int4*)(slot + e4) = sl;
        }
    } else {
        // all four W -> chunk-major bf16: Wt[(k/8)*N + n][j] = W[(k/8)*8+j, n]
        int id = (b - PREP_CONVX_BLK - PREP_INDEG_BLK) * 256 + threadIdx.x;
        const float* W; unsigned short* T; int N, base;
        if      (id <  24576) { W = W0; T = T0; N = 192; base = 0;     }
        else if (id <  61440) { W = W1; T = T1; N = 192; base = 24576; }
        else if (id <  98304) { W = W2; T = T2; N = 192; base = 61440; }
        else                  { W = W3; T = T3; N = 128; base = 98304; }
        int lid = id - base;
        int ci = lid >> 3, j = lid & 7;
        int kc = ci / N, n = ci % N;
        T[lid] = (unsigned short)fb(W[(kc * 8 + j) * N + n]);
    }
}

// ---------------- scan of indeg -> offs (exclusive, offs[0]=0, offs[NN]=NE) ----------------
__global__ __launch_bounds__(1024) void k_scan1(const int* __restrict__ indeg, int* __restrict__ offs,
                                                int* __restrict__ partials) {
    __shared__ int s[1024];
    int t = threadIdx.x;
    int gid = blockIdx.x * 1024 + t;
    int v = (gid < NN) ? indeg[gid] : 0;
    s[t] = v;
    __syncthreads();
    for (int d = 1; d < 1024; d <<= 1) {
        int tv = (t >= d) ? s[t - d] : 0;
        __syncthreads();
        s[t] += tv;
        __syncthreads();
    }
    if (gid < NN) offs[gid + 1] = s[t];
    if (t == 1023) partials[blockIdx.x] = s[1023];
}

__global__ __launch_bounds__(128) void k_scan2(int* __restrict__ offs, int* __restrict__ partials) {
    __shared__ int s[128];
    int t = threadIdx.x;
    int v = (t < NB_SCAN) ? partials[t] : 0;
    s[t] = v;
    __syncthreads();
    for (int d = 1; d < 128; d <<= 1) {
        int tv = (t >= d) ? s[t - d] : 0;
        __syncthreads();
        s[t] += tv;
        __syncthreads();
    }
    if (t < NB_SCAN) partials[t] = s[t] - v;   // exclusive
    if (t == 0) offs[0] = 0;
}

__global__ __launch_bounds__(1024) void k_scan3(int* __restrict__ offs, const int* __restrict__ partials) {
    int gid = blockIdx.x * 1024 + threadIdx.x;
    if (gid < NN) offs[gid + 1] += partials[blockIdx.x];
}

// ---------------- atomic-free CSR fill: csr[offs[dst] + slot[e]] = src[e] ----------------
__global__ __launch_bounds__(256) void k_fill(const int* __restrict__ ei, const int* __restrict__ offs,
                                              const int* __restrict__ slot, int* __restrict__ csr) {
    int e4 = (blockIdx.x * 256 + threadIdx.x) * 4;
    if (e4 >= NE) return;
    int4 sv = *(const int4*)(ei + e4);
    int4 dv = *(const int4*)(ei + NE + e4);
    int4 sl = *(const int4*)(slot + e4);
    csr[offs[dv.x] + sl.x] = sv.x;
    csr[offs[dv.y] + sl.y] = sv.y;
    csr[offs[dv.z] + sl.z] = sv.z;
    csr[offs[dv.w] + sl.w] = sv.w;
}

// ---------------- aggregation: y[i] = x[i] + eps*deg + sum relu(A[src]) -> Yout ----------------
// One wave per node; per-edge index work is scalar (s_load edge ids, s_cselect tail->zero row).
__global__ __launch_bounds__(256, 8) void k_agg192(const unsigned short* __restrict__ Ain,
                                                   unsigned short* __restrict__ Yout,
                                                   const int* __restrict__ offs,
                                                   const int* __restrict__ indeg,
                                                   const int* __restrict__ csr) {
    const int w = threadIdx.x >> 6, lane = threadIdx.x & 63;
    const int i = __builtin_amdgcn_readfirstlane(blockIdx.x * 4 + w);
    const bool act = lane < 48;
    const int deg   = __builtin_amdgcn_readfirstlane(indeg[i]);
    const int start = __builtin_amdgcn_readfirstlane(offs[i]);
    const int fo = (act ? lane : 47) * 8;          // clamped byte offset within row
    const char* Ab = (const char*)Ain;

    f32x2 A01, A23;
    {   // residual (not relu'd) + eps*deg
        uint2 p = *(const uint2*)(Ab + (size_t)i * 384 + fo);
        const float ed = 1e-7f * (float)deg;
        A01 = (f32x2){bl(p.x) + ed, bh(p.x) + ed};
        A23 = (f32x2){bl(p.y) + ed, bh(p.y) + ed};
    }

    const int* ecsr = csr + start;                 // wave-uniform
    for (int e = 0; e < deg; e += 16) {
        unsigned int off[16];
#pragma unroll
        for (int k = 0; k < 16; k++) {
            int v = ecsr[e + k];                   // uniform -> s_load (over-read is ws slack)
            off[k] = (e + k < deg) ? (unsigned int)v * 384u : ZOFF;   // s_cselect
        }
        uint2 p[16];
#pragma unroll
        for (int k = 0; k < 16; k++)
            p[k] = *(const uint2*)(Ab + (size_t)off[k] + fo);   // sgpr-base + lane offset
#pragma unroll
        for (int k = 0; k < 16; k++) {
            unsigned int rx = prelu(p[k].x), ry = prelu(p[k].y);
            A01 += (f32x2){bl(rx), bh(rx)};
            A23 += (f32x2){bl(ry), bh(ry)};
        }
    }
    if (act) {
        uint2 o;
        o.x = fb(A01.x) | (fb(A01.y) << 16);
        o.y = fb(A23.x) | (fb(A23.y) << 16);
        *(uint2*)(Yout + (size_t)i * S + lane * 4) = o;
    }
}

__global__ __launch_bounds__(256, 8) void k_agg128(const unsigned short* __restrict__ Ain,
                                                   unsigned short* __restrict__ Yout,
                                                   const int* __restrict__ offs,
                                                   const int* __restrict__ indeg,
                                                   const int* __restrict__ csr) {
    const int w = threadIdx.x >> 6, lane = threadIdx.x & 63;
    const int i = __builtin_amdgcn_readfirstlane(blockIdx.x * 4 + w);
    const int deg   = __builtin_amdgcn_readfirstlane(indeg[i]);
    const int start = __builtin_amdgcn_readfirstlane(offs[i]);
    const int fo = lane * 4;                       // 64 lanes x 2 feats = 256B row payload
    const char* Ab = (const char*)Ain;

    f32x2 A01;
    {
        unsigned int p = *(const unsigned int*)(Ab + (size_t)i * 384 + fo);
        const float ed = 1e-7f * (float)deg;
        A01 = (f32x2){bl(p) + ed, bh(p) + ed};
    }

    const int* ecsr = csr + start;
    for (int e = 0; e < deg; e += 16) {
        unsigned int off[16];
#pragma unroll
        for (int k = 0; k < 16; k++) {
            int v = ecsr[e + k];
            off[k] = (e + k < deg) ? (unsigned int)v * 384u : ZOFF;
        }
        unsigned int q[16];
#pragma unroll
        for (int k = 0; k < 16; k++)
            q[k] = *(const unsigned int*)(Ab + (size_t)off[k] + fo);
#pragma unroll
        for (int k = 0; k < 16; k++) {
            unsigned int r = prelu(q[k]);
            A01 += (f32x2){bl(r), bh(r)};
        }
    }
    *(unsigned int*)(Yout + (size_t)i * S + lane * 2) =
        fb(A01.x) | (fb(A01.y) << 16);
}

// ---------------- GEMM: h = y @ W + b (R6 orientation: lane = col, coalesced row stores) ----
template <int K, int N>
__global__ __launch_bounds__(256) void k_gemm(const unsigned short* __restrict__ Yin,
                                              const unsigned short* __restrict__ WtC,
                                              const float* __restrict__ bias,
                                              unsigned short* __restrict__ Aout) {
    static_assert(K % 16 == 0 && N % 32 == 0, "");
    const int w = threadIdx.x >> 6, lane = threadIdx.x & 63;
    const int rt = blockIdx.x * 4 + w;
    if (rt >= (NN / 32)) return;
    const int hl = lane >> 5, lr = lane & 31;
    const int row0 = rt * 32;
    f32x16 acc[N / 32];
#pragma unroll
    for (int c = 0; c < N / 32; c++)
#pragma unroll
        for (int r = 0; r < 16; r++) acc[c][r] = 0.f;

    const unsigned short* ap = Yin + (row0 + lr) * S + hl * 8;
    const uint4* b4 = (const uint4*)WtC;
#pragma unroll
    for (int ks = 0; ks < K / 16; ks++) {
        U16x4 a;
        a.u = *(const uint4*)(ap + ks * 16);
#pragma unroll
        for (int c = 0; c < N / 32; c++) {
            U16x4 b;
            b.u = b4[(ks * 2 + hl) * N + c * 32 + lr];
            acc[c] = __builtin_amdgcn_mfma_f32_32x32x16_bf16(a.b, b.b, acc[c], 0, 0, 0);
        }
    }
#pragma unroll
    for (int c = 0; c < N / 32; c++) {
        const int col = c * 32 + lr;
        const float bc = bias[col];
#pragma unroll
        for (int r = 0; r < 16; r++) {
            const int row = row0 + (r & 3) + 8 * (r >> 2) + 4 * hl;
            Aout[row * S + col] = (unsigned short)fb(acc[c][r] + bc);
        }
    }
}

// ---------------- pooling + head ----------------
__global__ __launch_bounds__(128) void k_pool(const unsigned short* __restrict__ A_, const int* __restrict__ batch,
                                              float* __restrict__ sums, float* __restrict__ cnt) {
    const int b = blockIdx.x;      // 500 blocks x 200 nodes
    const int f = threadIdx.x;     // 128 features
    int n0 = b * 200;
    int n1 = min(n0 + 200, NN);
    int cur = batch[n0];
    float acc = 0.f;
    int run = 0;
    for (int n = n0; n < n1; n++) {
        int g = batch[n];
        if (g != cur) {
            atomicAdd(&sums[cur * 128 + f], acc);
            if (f == 0) atomicAdd(&cnt[cur], (float)run);
            acc = 0.f; run = 0; cur = g;
        }
        acc += __uint_as_float(((unsigned int)A_[(size_t)n * S + f]) << 16);
        run++;
    }
    atomicAdd(&sums[cur * 128 + f], acc);
    if (f == 0) atomicAdd(&cnt[cur], (float)run);
}

__global__ __launch_bounds__(64) void k_head(const float* __restrict__ sums, const float* __restrict__ cnt,
                                             const float* __restrict__ Wfc, const float* __restrict__ bfc,
                                             float* __restrict__ out) {
    __shared__ float pooled[128];
    __shared__ float lg[10];
    const int g = blockIdx.x, t = threadIdx.x;
    float inv = 1.f / fmaxf(cnt[g], 1.f);
    pooled[t]      = sums[g * 128 + t] * inv;
    pooled[t + 64] = sums[g * 128 + t + 64] * inv;
    __syncthreads();
    if (t < 10) {
        float s = bfc[t];
        for (int f = 0; f < 128; f++) s += pooled[f] * Wfc[f * 10 + t];
        lg[t] = s;
    }
    __syncthreads();
    if (t < 10) {
        float m = lg[0];
        for (int k = 1; k < 10; k++) m = fmaxf(m, lg[k]);
        float se = 0.f;
        for (int k = 0; k < 10; k++) se += expf(lg[k] - m);
        out[g * 10 + t] = lg[t] - m - logf(se);
    }
}

// ---------------- workspace layout (bytes) ----------------
constexpr size_t A0_OFF     = 0;                    // 38,400,384 (incl zero row NN)
constexpr size_t A1_OFF     = 38400384;             // 38,400,000 (first 6.4MB doubles as slot[])
constexpr size_t CSR_OFF    = 76800384;             // 6,400,000
constexpr size_t OFFS_OFF   = 83200384;             // 400,128 (100001 ints padded)
constexpr size_t INDEG_OFF  = 83600512;             // 400,000
constexpr size_t PART_OFF   = 84000512;             // 512
constexpr size_t WT0_OFF    = 84001024;             // 49,152
constexpr size_t WT1_OFF    = 84050176;             // 73,728
constexpr size_t WT2_OFF    = 84123904;             // 73,728
constexpr size_t WT3_OFF    = 84197632;             // 49,152
constexpr size_t SUMS_OFF   = 84246784;             // 32,768
constexpr size_t CNT_OFF    = 84279552;             // 256

extern "C" void kernel_launch(void* const* d_in, const int* in_sizes, int n_in,
                              void* d_out, int out_size, void* d_ws, size_t ws_size,
                              hipStream_t stream) {
    const float* x   = (const float*)d_in[0];
    const float* W0  = (const float*)d_in[1];
    const float* b0  = (const float*)d_in[2];
    const float* W1  = (const float*)d_in[3];
    const float* b1  = (const float*)d_in[4];
    const float* W2  = (const float*)d_in[5];
    const float* b2  = (const float*)d_in[6];
    const float* W3  = (const float*)d_in[7];
    const float* b3  = (const float*)d_in[8];
    const float* Wfc = (const float*)d_in[9];
    const float* bfc = (const float*)d_in[10];
    const int*   ei  = (const int*)d_in[11];
    const int*   bat = (const int*)d_in[12];
    float* out = (float*)d_out;

    char* ws = (char*)d_ws;
    unsigned short* A0  = (unsigned short*)(ws + A0_OFF);
    unsigned short* A1  = (unsigned short*)(ws + A1_OFF);
    int* slot   = (int*)(ws + A1_OFF);              // aliases A1; consumed before A1 is written
    int* csr    = (int*)(ws + CSR_OFF);
    int* offs   = (int*)(ws + OFFS_OFF);
    int* indeg  = (int*)(ws + INDEG_OFF);
    int* part   = (int*)(ws + PART_OFF);
    unsigned short* Wt0 = (unsigned short*)(ws + WT0_OFF);
    unsigned short* Wt1 = (unsigned short*)(ws + WT1_OFF);
    unsigned short* Wt2 = (unsigned short*)(ws + WT2_OFF);
    unsigned short* Wt3 = (unsigned short*)(ws + WT3_OFF);
    float* sums = (float*)(ws + SUMS_OFF);
    float* cnt  = (float*)(ws + CNT_OFF);

    // zero indeg and pool sums+cnt
    hipMemsetAsync(ws + INDEG_OFF, 0, 400000, stream);
    hipMemsetAsync(ws + SUMS_OFF, 0, 33024, stream);

    // fused preprocessing: convx | indeg+slot | convw4
    k_prep<<<PREP_GRID, 256, 0, stream>>>(x, ei, W0, W1, W2, W3, A0, indeg, slot,
                                          Wt0, Wt1, Wt2, Wt3);

    // offs = exclusive scan(indeg)
    k_scan1<<<NB_SCAN, 1024, 0, stream>>>(indeg, offs, part);
    k_scan2<<<1, 128, 0, stream>>>(offs, part);
    k_scan3<<<NB_SCAN, 1024, 0, stream>>>(offs, part);

    // atomic-free CSR fill (single pass)
    k_fill<<<(NE / 4 + 255) / 256, 256, 0, stream>>>(ei, offs, slot, csr);

    const int AGG_GRID  = NN / 4;                   // 25000 blocks, 1 wave/node
    const int GEMM_GRID = (NN / 32 + 3) / 4;        // 782 blocks, 1 wave/32-row tile

    // ping-pong: x/h live in A0 (with zero row), y lives in A1
    k_agg128<<<AGG_GRID, 256, 0, stream>>>(A0, A1, offs, indeg, csr);
    k_gemm<128, 192><<<GEMM_GRID, 256, 0, stream>>>(A1, Wt0, b0, A0);
    k_agg192<<<AGG_GRID, 256, 0, stream>>>(A0, A1, offs, indeg, csr);
    k_gemm<192, 192><<<GEMM_GRID, 256, 0, stream>>>(A1, Wt1, b1, A0);
    k_agg192<<<AGG_GRID, 256, 0, stream>>>(A0, A1, offs, indeg, csr);
    k_gemm<192, 192><<<GEMM_GRID, 256, 0, stream>>>(A1, Wt2, b2, A0);
    k_agg192<<<AGG_GRID, 256, 0, stream>>>(A0, A1, offs, indeg, csr);
    k_gemm<192, 128><<<GEMM_GRID, 256, 0, stream>>>(A1, Wt3, b3, A0);

    // pool + head
    k_pool<<<500, 128, 0, stream>>>(A0, bat, sums, cnt);
    k_head<<<NG, 64, 0, stream>>>(sums, cnt, Wfc, bfc, out);
}